// Round 13
// baseline (1196.030 us; speedup 1.0000x reference)
//
#include <hip/hip_runtime.h>

#define DEV __device__ __forceinline__

typedef __bf16 bf16x8 __attribute__((ext_vector_type(8)));
typedef float f32x4 __attribute__((ext_vector_type(4)));
typedef unsigned short u16x4 __attribute__((ext_vector_type(4)));

DEV unsigned short f2bf(float f) {
    unsigned u = __builtin_bit_cast(unsigned, f);
    u += 0x7fffu + ((u >> 16) & 1u);   // round-to-nearest-even
    return (unsigned short)(u >> 16);
}

DEV float bf2f(unsigned short h) {
    unsigned u = (unsigned)h << 16;
    return __builtin_bit_cast(float, u);
}

// zero counts[N] + stats[1536]; pre-convert W1,W2 (6 mats) to bf16 [c][k];
// convert x -> xb bf16; block 0 detects int64-vs-int32 edge_index layout.
__global__ __launch_bounds__(256) void setup_kernel(
    const int* __restrict__ ei, int* __restrict__ flag,
    int* __restrict__ counts, float* __restrict__ stats,
    const float* __restrict__ W1, const float* __restrict__ W2,
    unsigned short* __restrict__ Wt,
    const float* __restrict__ x, unsigned short* __restrict__ xb, int N)
{
    int g = blockIdx.x * 256 + threadIdx.x;
    if (g < N) counts[g] = 0;
    if (g < 1536) stats[g] = 0.f;
    if (g < 12288) {                       // 6 mats x 16 k-groups x 128 cols
        int mat = g >> 11;
        int r = g & 2047;
        int c = r & 127;
        int kg = (r >> 7) * 8;
        const float* Wsrc = (mat < 3) ? (W1 + (size_t)mat * 16384)
                                      : (W2 + (size_t)(mat - 3) * 16384);
        unsigned short o[8];
#pragma unroll
        for (int q = 0; q < 8; ++q)
            o[q] = f2bf(Wsrc[(size_t)(kg + q) * 128 + c]);
        *(uint4*)(Wt + ((size_t)mat * 128 + c) * 128 + kg) = *(const uint4*)o;
    }
    // x -> xb bf16 (8 elems/thread); N*16 threads cover N*128
    if (g < N * 16) {
        size_t base = (size_t)g * 8;
        float4 a = *(const float4*)(x + base);
        float4 b = *(const float4*)(x + base + 4);
        unsigned short o[8];
        o[0] = f2bf(a.x); o[1] = f2bf(a.y); o[2] = f2bf(a.z); o[3] = f2bf(a.w);
        o[4] = f2bf(b.x); o[5] = f2bf(b.y); o[6] = f2bf(b.z); o[7] = f2bf(b.w);
        *(uint4*)(xb + base) = *(const uint4*)o;
    }
    if (blockIdx.x == 0 && threadIdx.x < 64) {
        int t = threadIdx.x;
        int v = (t < 32) ? ei[2 * t + 1] : 0;
        unsigned long long b = __ballot(v == 0);
        if (t == 0) *flag = (b == ~0ull) ? 1 : 0;
    }
}

__global__ __launch_bounds__(256) void hist_kernel(
    const int* __restrict__ ei, const int* __restrict__ i64flag,
    int* __restrict__ counts, int E)
{
    int e = blockIdx.x * 256 + threadIdx.x;
    if (e >= E) return;
    int d = (*i64flag) ? ei[2 * (size_t)E + 2 * (size_t)e] : ei[(size_t)E + e];
    atomicAdd(&counts[d], 1);
}

// block-level inclusive scan; writes per-element exclusive offsets + block totals
__global__ __launch_bounds__(256) void scan1_kernel(
    const int* __restrict__ counts, int* __restrict__ offs,
    int* __restrict__ bsum, int N)
{
    __shared__ int s[256];
    int tid = threadIdx.x;
    int i = blockIdx.x * 256 + tid;
    int c = (i < N) ? counts[i] : 0;
    s[tid] = c;
    __syncthreads();
#pragma unroll
    for (int off = 1; off < 256; off <<= 1) {
        int add = (tid >= off) ? s[tid - off] : 0;
        __syncthreads();
        s[tid] += add;
        __syncthreads();
    }
    int incl = s[tid];
    if (i < N) offs[i] = incl - c;            // exclusive within block
    if (tid == 255) bsum[blockIdx.x] = incl;  // block total
}

// merged scan2+scan3: every block re-scans the (<=256) block sums in LDS,
// adds its prefix to offs, fills cursor, and block 0 writes offs[N] = E.
__global__ __launch_bounds__(256) void scan23_kernel(
    int* __restrict__ offs, const int* __restrict__ bsum,
    int* __restrict__ cursor, int N, int E, int nb)
{
    __shared__ int s[256];
    int tid = threadIdx.x;
    int v = (tid < nb) ? bsum[tid] : 0;
    s[tid] = v;
    __syncthreads();
#pragma unroll
    for (int off = 1; off < 256; off <<= 1) {
        int add = (tid >= off) ? s[tid - off] : 0;
        __syncthreads();
        s[tid] += add;
        __syncthreads();
    }
    int pre = (blockIdx.x == 0) ? 0 : s[blockIdx.x - 1];
    int i = blockIdx.x * 256 + tid;
    if (i < N) {
        int o = offs[i] + pre;
        offs[i] = o;
        cursor[i] = o;
    }
    if (blockIdx.x == 0 && tid == 0) offs[N] = E;
}

// CSR scatter: el[slot] = (src, edge_id)
__global__ __launch_bounds__(256) void scatter_kernel(
    const int* __restrict__ ei, const int* __restrict__ i64flag,
    int* __restrict__ cursor, int2* __restrict__ el, int E)
{
    int e = blockIdx.x * 256 + threadIdx.x;
    if (e >= E) return;
    int s, d;
    if (*i64flag) {
        s = ei[2 * (size_t)e];
        d = ei[2 * (size_t)E + 2 * (size_t)e];
    } else {
        s = ei[e];
        d = ei[(size_t)E + e];
    }
    int pos = atomicAdd(&cursor[d], 1);
    el[pos] = make_int2(s, e);
}

// ---------------- layer-0 aggregation (full-width, R12 structure) ----------
// t1[n] (bf16) = xb[n] + sum_slots relu(xb[el.x] + ea[el.y]); also writes
// eab[slot] = bf16(ea row) in CSR order and srcs[slot] = el.x for later layers.
__global__ __launch_bounds__(512) void agg0_kernel(
    const unsigned short* __restrict__ xb, const float* __restrict__ ea,
    unsigned short* __restrict__ eab, int* __restrict__ srcs,
    const int2* __restrict__ el, const int* __restrict__ offs,
    unsigned short* __restrict__ t1, int N)
{
    int tid = threadIdx.x;
    const int lane = tid & 63;
    const int half = lane >> 5;
    const int l32  = lane & 31;
    const int d0   = l32 * 4;

    const int n = blockIdx.x * 8 + (tid >> 6);
    if (n >= N) return;

    const int start = offs[n];
    const int deg   = offs[n + 1] - start;
    const int mid = (deg + 1) >> 1;
    int j        = half ? mid : 0;
    const int hi = half ? deg : mid;

    f32x4 acc = {0.f, 0.f, 0.f, 0.f};
    if (half == 0) {
        u16x4 cv = *(const u16x4*)(xb + (size_t)n * 128 + d0);
#pragma unroll
        for (int q = 0; q < 4; ++q) acc[q] = bf2f(cv[q]);
    }

#define APPLY(GXV, AV) { \
    _Pragma("unroll") \
    for (int q = 0; q < 4; ++q) \
        acc[q] += fmaxf(bf2f((GXV)[q]) + (AV)[q], 0.f); }

    for (; j + 3 < hi; j += 4) {
        int2 e0 = el[start + j + 0];
        int2 e1 = el[start + j + 1];
        int2 e2 = el[start + j + 2];
        int2 e3 = el[start + j + 3];
        u16x4 x0 = *(const u16x4*)(xb + (size_t)e0.x * 128 + d0);
        u16x4 x1 = *(const u16x4*)(xb + (size_t)e1.x * 128 + d0);
        u16x4 x2 = *(const u16x4*)(xb + (size_t)e2.x * 128 + d0);
        u16x4 x3 = *(const u16x4*)(xb + (size_t)e3.x * 128 + d0);
        f32x4 a0 = __builtin_nontemporal_load((const f32x4*)(ea + (size_t)e0.y * 128 + d0));
        f32x4 a1 = __builtin_nontemporal_load((const f32x4*)(ea + (size_t)e1.y * 128 + d0));
        f32x4 a2 = __builtin_nontemporal_load((const f32x4*)(ea + (size_t)e2.y * 128 + d0));
        f32x4 a3 = __builtin_nontemporal_load((const f32x4*)(ea + (size_t)e3.y * 128 + d0));
        u16x4 b0, b1, b2, b3;
#pragma unroll
        for (int q = 0; q < 4; ++q) {
            b0[q] = f2bf(a0[q]); b1[q] = f2bf(a1[q]);
            b2[q] = f2bf(a2[q]); b3[q] = f2bf(a3[q]);
        }
        __builtin_nontemporal_store(b0, (u16x4*)(eab + (size_t)(start + j + 0) * 128 + d0));
        __builtin_nontemporal_store(b1, (u16x4*)(eab + (size_t)(start + j + 1) * 128 + d0));
        __builtin_nontemporal_store(b2, (u16x4*)(eab + (size_t)(start + j + 2) * 128 + d0));
        __builtin_nontemporal_store(b3, (u16x4*)(eab + (size_t)(start + j + 3) * 128 + d0));
        if (l32 == 0) {
            srcs[start + j + 0] = e0.x;
            srcs[start + j + 1] = e1.x;
            srcs[start + j + 2] = e2.x;
            srcs[start + j + 3] = e3.x;
        }
        APPLY(x0, a0); APPLY(x1, a1); APPLY(x2, a2); APPLY(x3, a3);
    }
    for (; j < hi; ++j) {
        int2 e0 = el[start + j];
        u16x4 x0 = *(const u16x4*)(xb + (size_t)e0.x * 128 + d0);
        f32x4 a0 = __builtin_nontemporal_load((const f32x4*)(ea + (size_t)e0.y * 128 + d0));
        u16x4 b0;
#pragma unroll
        for (int q = 0; q < 4; ++q) b0[q] = f2bf(a0[q]);
        __builtin_nontemporal_store(b0, (u16x4*)(eab + (size_t)(start + j) * 128 + d0));
        if (l32 == 0) srcs[start + j] = e0.x;
        APPLY(x0, a0);
    }
#undef APPLY

#pragma unroll
    for (int q = 0; q < 4; ++q) acc[q] += __shfl_xor(acc[q], 32);

    if (half == 0) {
        u16x4 o;
        o[0] = f2bf(acc[0]); o[1] = f2bf(acc[1]);
        o[2] = f2bf(acc[2]); o[3] = f2bf(acc[3]);
        *(u16x4*)(t1 + (size_t)n * 128 + d0) = o;
    }
}

// ---------------- layers 1-2 aggregation: 4-pass dimension-split -----------
// Pass p covers dims [p*32, p*32+32). Per pass the random-gathered xb slice is
// 50000 x 32 x 2B = 3.2 MB -- fits each XCD's 4 MB L2, turning the gather into
// an L2 hit. ea/index streams use NT loads so they don't evict the slice.
// Wave = 1 node; 8 groups of 8 lanes; group g handles CSR slot start+j+g,
// each lane 4 dims. Cross-group combine via shfl_xor(8,16,32).
__global__ __launch_bounds__(512) void agg4_kernel(
    const unsigned short* __restrict__ xb, const unsigned short* __restrict__ eab,
    const int* __restrict__ srcs, const int* __restrict__ offs,
    const float* __restrict__ statsIn, const float* __restrict__ gamma,
    const float* __restrict__ beta,
    unsigned short* __restrict__ t1, int N, int pass)
{
    __shared__ float sc[128], sh[128];
    int tid = threadIdx.x;
    if (tid < 128) {
        float inv = 1.f / (float)N;
        float m = statsIn[tid] * inv;
        float v = statsIn[128 + tid] * inv - m * m;
        v = fmaxf(v, 0.f);
        float rs = rsqrtf(v + 1e-5f);
        float gr = gamma[tid] * rs;
        sc[tid] = gr;
        sh[tid] = beta[tid] - m * gr;
    }
    __syncthreads();

    const int lane = tid & 63;
    const int g    = lane >> 3;          // edge group 0..7
    const int sub  = lane & 7;           // dim sub-slot 0..7
    const int dbase = pass * 32 + sub * 4;

    f32x4 scv = *(const f32x4*)(sc + dbase);
    f32x4 shv = *(const f32x4*)(sh + dbase);

    const int n = blockIdx.x * 8 + (tid >> 6);
    if (n >= N) return;

    const int start = offs[n];
    const int deg   = offs[n + 1] - start;

    f32x4 acc = {0.f, 0.f, 0.f, 0.f};
    for (int j = 0; j < deg; j += 8) {
        int rel = j + g;
        if (rel < deg) {
            int slot = start + rel;
            int src = srcs[slot];
            u16x4 xv = *(const u16x4*)(xb + (size_t)src * 128 + dbase);
            u16x4 ev = __builtin_nontemporal_load(
                (const u16x4*)(eab + (size_t)slot * 128 + dbase));
#pragma unroll
            for (int q = 0; q < 4; ++q) {
                float gx = fmaxf(fmaf(bf2f(xv[q]), scv[q], shv[q]), 0.f);
                acc[q] += fmaxf(gx + bf2f(ev[q]), 0.f);
            }
        }
    }
    // reduce the 8 edge-groups (lane bits 3..5)
#pragma unroll
    for (int q = 0; q < 4; ++q) {
        acc[q] += __shfl_xor(acc[q], 8);
        acc[q] += __shfl_xor(acc[q], 16);
        acc[q] += __shfl_xor(acc[q], 32);
    }

    if (g == 0) {
        u16x4 cv = *(const u16x4*)(xb + (size_t)n * 128 + dbase);
        u16x4 o;
#pragma unroll
        for (int q = 0; q < 4; ++q) {
            float f = fmaxf(fmaf(bf2f(cv[q]), scv[q], shv[q]), 0.f);
            o[q] = f2bf(f + acc[q]);
        }
        __builtin_nontemporal_store(o, (u16x4*)(t1 + (size_t)n * 128 + dbase));
    }
}

// ---------------- GEMM 128x128 tile, 8 waves, fused BN-affine + col stats
// out[n][c] = sum_k a[n][k]*Wt[c][k] + bias[c].  Wt bf16 [c][k]; inp bf16.
// BNA: a = bf16(relu(inp*sc+sh)); else a = inp.
// OUTBF: out stored bf16, else f32. Stats accumulate on pre-round f32 values.
template<bool BNA, bool OUTBF>
__global__ __launch_bounds__(512) void gemm_kernel(
    const unsigned short* __restrict__ inp,   // [N][128] bf16
    const unsigned short* __restrict__ Wt,    // [128][128] bf16, [c][k]
    const float* __restrict__ bias,           // [128] f32
    const float* __restrict__ statsIn,
    const float* __restrict__ gA, const float* __restrict__ bA,
    void* __restrict__ outv, float* __restrict__ statsOut, int N)
{
    __shared__ __attribute__((aligned(16))) unsigned short As[128][136];  // [r][k]
    __shared__ __attribute__((aligned(16))) unsigned short Ws[128][136];  // [c][k]
    __shared__ float u0[128], u1[128];  // BNA: sc/sh during staging; then stats
    const int tid = threadIdx.x;
    const int row0 = blockIdx.x * 128;

    if (BNA) {
        if (tid < 128) {
            float inv = 1.f / (float)N;
            float m = statsIn[tid] * inv;
            float v = statsIn[128 + tid] * inv - m * m;
            v = fmaxf(v, 0.f);
            float rs = rsqrtf(v + 1e-5f);
            float gr = gA[tid] * rs;
            u0[tid] = gr;
            u1[tid] = bA[tid] - m * gr;
        }
        __syncthreads();
    }

    // stage Wt -> Ws: 16384 elems, 512 thr x 8 elems x 4 iters
#pragma unroll
    for (int it = 0; it < 4; ++it) {
        int lin = (it * 512 + tid) * 8;
        int c = lin >> 7;
        int k = lin & 127;
        *(uint4*)&Ws[c][k] = *(const uint4*)(Wt + (size_t)c * 128 + k);
    }
    // stage A tile: 128x128 bf16, 4 iters (zero-pad tail rows)
#pragma unroll
    for (int it = 0; it < 4; ++it) {
        int lin = (it * 512 + tid) * 8;
        int r = lin >> 7;
        int c = lin & 127;
        int row = row0 + r;
        if (row < N) {
            uint4 v = *(const uint4*)(inp + (size_t)row * 128 + c);
            if (BNA) {
                const unsigned short* pv = (const unsigned short*)&v;
                unsigned short o[8];
#pragma unroll
                for (int q = 0; q < 8; ++q)
                    o[q] = f2bf(fmaxf(fmaf(bf2f(pv[q]), u0[c + q], u1[c + q]), 0.f));
                *(uint4*)&As[r][c] = *(const uint4*)o;
            } else {
                *(uint4*)&As[r][c] = v;
            }
        } else {
            uint4 z = {0u, 0u, 0u, 0u};
            *(uint4*)&As[r][c] = z;
        }
    }
    __syncthreads();
    // repurpose u0/u1 as column sum / sumsq accumulators
    if (tid < 128) { u0[tid] = 0.f; u1[tid] = 0.f; }
    __syncthreads();

    const int wave = tid >> 6;          // 0..7, owns rows wave*16..+15
    const int lane = tid & 63;
    const int quad = lane >> 4;
    const int m16  = lane & 15;

    bf16x8 af[4];
#pragma unroll
    for (int kk = 0; kk < 4; ++kk)
        af[kk] = *reinterpret_cast<const bf16x8*>(
            &As[wave * 16 + m16][kk * 32 + quad * 8]);

    float* outf = (float*)outv;
    unsigned short* outb = (unsigned short*)outv;

#pragma unroll
    for (int ct = 0; ct < 8; ++ct) {
        f32x4 acc = {0.f, 0.f, 0.f, 0.f};
#pragma unroll
        for (int kk = 0; kk < 4; ++kk) {
            bf16x8 bf = *reinterpret_cast<const bf16x8*>(&Ws[ct * 16 + m16][kk * 32 + quad * 8]);
            acc = __builtin_amdgcn_mfma_f32_16x16x32_bf16(af[kk], bf, acc, 0, 0, 0);
        }
        int col = ct * 16 + m16;
        float bb = bias[col];
        float s_part = 0.f, q_part = 0.f;
#pragma unroll
        for (int r = 0; r < 4; ++r) {
            int row = row0 + wave * 16 + quad * 4 + r;  // C/D: row = quad*4+reg
            if (row < N) {
                float val = acc[r] + bb;
                if (OUTBF) outb[(size_t)row * 128 + col] = f2bf(val);
                else       outf[(size_t)row * 128 + col] = val;
                s_part += val;
                q_part += val * val;
            }
        }
        // reduce over the 4 quad-groups that share this column (lanes ^16, ^32)
        s_part += __shfl_xor(s_part, 16); q_part += __shfl_xor(q_part, 16);
        s_part += __shfl_xor(s_part, 32); q_part += __shfl_xor(q_part, 32);
        if (lane < 16) {
            atomicAdd(&u0[col], s_part);
            atomicAdd(&u1[col], q_part);
        }
    }
    __syncthreads();
    if (tid < 128) {
        atomicAdd(&statsOut[tid],       u0[tid]);
        atomicAdd(&statsOut[128 + tid], u1[tid]);
    }
}

// out = gamma * (t - mean) * rsqrt(var + eps) + beta  (final layer, no relu)
__global__ __launch_bounds__(256) void bn_kernel(
    const float* __restrict__ t, const float* __restrict__ sum, const float* __restrict__ sq,
    const float* __restrict__ gamma, const float* __restrict__ beta,
    float* __restrict__ out, int N, int nv4)
{
    __shared__ float sc[128], sh[128];
    int tid = threadIdx.x;
    if (tid < 128) {
        float inv = 1.f / (float)N;
        float m = sum[tid] * inv;
        float v = sq[tid] * inv - m * m;
        v = fmaxf(v, 0.f);
        float rs = rsqrtf(v + 1e-5f);
        float gr = gamma[tid] * rs;
        sc[tid] = gr;
        sh[tid] = beta[tid] - m * gr;
    }
    __syncthreads();
    int g = blockIdx.x * 256 + tid;
    if (g < nv4) {
        int c = (g & 31) * 4;
        float4 v = *(const float4*)(t + (size_t)g * 4);
        float4 o;
        o.x = v.x * sc[c + 0] + sh[c + 0];
        o.y = v.y * sc[c + 1] + sh[c + 1];
        o.z = v.z * sc[c + 2] + sh[c + 2];
        o.w = v.w * sc[c + 3] + sh[c + 3];
        *(float4*)(out + (size_t)g * 4) = o;
    }
}

extern "C" void kernel_launch(void* const* d_in, const int* in_sizes, int n_in,
                              void* d_out, int out_size, void* d_ws, size_t ws_size,
                              hipStream_t stream)
{
    const float* x  = (const float*)d_in[0];
    const int* ei   = (const int*)d_in[1];
    const float* ea = (const float*)d_in[2];
    // d_in[3] = batch (unused)
    const float* W1 = (const float*)d_in[4];
    const float* b1 = (const float*)d_in[5];
    const float* gm = (const float*)d_in[6];
    const float* bm = (const float*)d_in[7];
    const float* W2 = (const float*)d_in[8];
    const float* b2 = (const float*)d_in[9];
    const float* go = (const float*)d_in[10];
    const float* bo = (const float*)d_in[11];
    float* out = (float*)d_out;

    const int N = in_sizes[0] / 128;   // 50000
    const int E = in_sizes[2] / 128;   // 800000

    char* w = (char*)d_ws;
    float* t3f  = (float*)w;            w += (size_t)N * 128 * 4;   // layer-2 gemm2 out, f32
    unsigned short* t3b = (unsigned short*)w; w += (size_t)N * 128 * 2;  // layers 0/1 gemm2 out
    unsigned short* t1 = (unsigned short*)w; w += (size_t)N * 128 * 2;  // agg out, bf16
    unsigned short* t2 = (unsigned short*)w; w += (size_t)N * 128 * 2;  // gemm1 out, bf16
    unsigned short* xb = (unsigned short*)w; w += (size_t)N * 128 * 2;  // x bf16 (layer 0)
    unsigned short* Wt = (unsigned short*)w; w += (size_t)6 * 16384 * 2; // W bf16 [c][k]
    float* stats = (float*)w;           w += 1536 * 4;              // 6 x (sum[128], sq[128])
    int* i64flag = (int*)w;             w += 16;
    int* counts  = (int*)w;             w += (size_t)N * 4;
    int* offs    = (int*)w;             w += (size_t)(N + 16) * 4;  // N+1 entries
    int* cursor  = (int*)w;             w += (size_t)N * 4;
    int* bsum    = (int*)w;             w += 256 * 4;
    int* srcs    = (int*)w;             w += (size_t)E * 4;         // slot -> src
    int2* el     = (int2*)w;            w += (size_t)E * 8;         // CSR: (src, edge)
    unsigned short* eab = (unsigned short*)w; w += (size_t)E * 128 * 2;  // ea bf16, CSR order

    const int nv4 = N * 32;
    const int gElem = (nv4 + 255) / 256;
    const int gGemm = (N + 127) / 128;
    const int gEdge = (E + 255) / 256;
    const int nb    = (N + 255) / 256;
    const int gAgg  = (N + 7) / 8;
    const int gConv = (N * 16 + 255) / 256;
    const int gSetup = gConv > nb ? gConv : nb;

    // ---- CSR build + W/x pre-convert (all layer-invariant) ----
    setup_kernel<<<gSetup, 256, 0, stream>>>(ei, i64flag, counts, stats, W1, W2, Wt, x, xb, N);
    hist_kernel<<<gEdge, 256, 0, stream>>>(ei, i64flag, counts, E);
    scan1_kernel<<<nb, 256, 0, stream>>>(counts, offs, bsum, N);
    scan23_kernel<<<nb, 256, 0, stream>>>(offs, bsum, cursor, N, E, nb);
    scatter_kernel<<<gEdge, 256, 0, stream>>>(ei, i64flag, cursor, el, E);

    for (int i = 0; i < 3; ++i) {
        float* sMlp = stats + (size_t)i * 512;        // gemm1 output stats
        float* sOut = stats + (size_t)i * 512 + 256;  // gemm2 output stats

        if (i == 0) {
            // layer 0: full-width; materializes eab (CSR order) + srcs
            agg0_kernel<<<gAgg, 512, 0, stream>>>(
                xb, ea, eab, srcs, el, offs, t1, N);
        } else {
            float* sPrev = stats + (size_t)(i - 1) * 512 + 256;
            // layers 1-2: 4 dimension-split passes; xb slice fits per-XCD L2
            for (int p = 0; p < 4; ++p) {
                agg4_kernel<<<gAgg, 512, 0, stream>>>(
                    t3b, eab, srcs, offs, sPrev, go + (i - 1) * 128, bo + (i - 1) * 128,
                    t1, N, p);
            }
        }
        // gemm1: t1 (bf16) -> t2 (bf16), stats of t2 -> sMlp
        gemm_kernel<false, true><<<gGemm, 512, 0, stream>>>(
            t1, Wt + (size_t)i * 16384, b1 + i * 128,
            nullptr, nullptr, nullptr, t2, sMlp, N);
        // gemm2: BN1+relu applied to t2; layers 0/1 -> t3b (bf16), layer 2 -> t3f (f32)
        if (i < 2) {
            gemm_kernel<true, true><<<gGemm, 512, 0, stream>>>(
                t2, Wt + (size_t)(i + 3) * 16384, b2 + i * 128,
                sMlp, gm + i * 128, bm + i * 128, t3b, sOut, N);
        } else {
            gemm_kernel<true, false><<<gGemm, 512, 0, stream>>>(
                t2, Wt + (size_t)(i + 3) * 16384, b2 + i * 128,
                sMlp, gm + i * 128, bm + i * 128, t3f, sOut, N);
        }
    }
    // final outer BN (no relu) -> out
    bn_kernel<<<gElem, 256, 0, stream>>>(t3f, stats + 2 * 512 + 256, stats + 2 * 512 + 384,
                                         go + 256, bo + 256, out, N, nv4);
}

// Round 14
// 1050.316 us; speedup vs baseline: 1.1387x; 1.1387x over previous
//
#include <hip/hip_runtime.h>

#define DEV __device__ __forceinline__

typedef __bf16 bf16x8 __attribute__((ext_vector_type(8)));
typedef float f32x4 __attribute__((ext_vector_type(4)));
typedef unsigned short u16x4 __attribute__((ext_vector_type(4)));

DEV unsigned short f2bf(float f) {
    unsigned u = __builtin_bit_cast(unsigned, f);
    u += 0x7fffu + ((u >> 16) & 1u);   // round-to-nearest-even
    return (unsigned short)(u >> 16);
}

DEV float bf2f(unsigned short h) {
    unsigned u = (unsigned)h << 16;
    return __builtin_bit_cast(float, u);
}

// zero counts[N] + stats[1536]; pre-convert W1,W2 (6 mats) to bf16 [c][k];
// convert x -> xb bf16; block 0 detects int64-vs-int32 edge_index layout.
__global__ __launch_bounds__(256) void setup_kernel(
    const int* __restrict__ ei, int* __restrict__ flag,
    int* __restrict__ counts, float* __restrict__ stats,
    const float* __restrict__ W1, const float* __restrict__ W2,
    unsigned short* __restrict__ Wt,
    const float* __restrict__ x, unsigned short* __restrict__ xb, int N)
{
    int g = blockIdx.x * 256 + threadIdx.x;
    if (g < N) counts[g] = 0;
    if (g < 1536) stats[g] = 0.f;
    if (g < 12288) {                       // 6 mats x 16 k-groups x 128 cols
        int mat = g >> 11;
        int r = g & 2047;
        int c = r & 127;
        int kg = (r >> 7) * 8;
        const float* Wsrc = (mat < 3) ? (W1 + (size_t)mat * 16384)
                                      : (W2 + (size_t)(mat - 3) * 16384);
        unsigned short o[8];
#pragma unroll
        for (int q = 0; q < 8; ++q)
            o[q] = f2bf(Wsrc[(size_t)(kg + q) * 128 + c]);
        *(uint4*)(Wt + ((size_t)mat * 128 + c) * 128 + kg) = *(const uint4*)o;
    }
    // x -> xb bf16 (8 elems/thread); N*16 threads cover N*128
    if (g < N * 16) {
        size_t base = (size_t)g * 8;
        float4 a = *(const float4*)(x + base);
        float4 b = *(const float4*)(x + base + 4);
        unsigned short o[8];
        o[0] = f2bf(a.x); o[1] = f2bf(a.y); o[2] = f2bf(a.z); o[3] = f2bf(a.w);
        o[4] = f2bf(b.x); o[5] = f2bf(b.y); o[6] = f2bf(b.z); o[7] = f2bf(b.w);
        *(uint4*)(xb + base) = *(const uint4*)o;
    }
    if (blockIdx.x == 0 && threadIdx.x < 64) {
        int t = threadIdx.x;
        int v = (t < 32) ? ei[2 * t + 1] : 0;
        unsigned long long b = __ballot(v == 0);
        if (t == 0) *flag = (b == ~0ull) ? 1 : 0;
    }
}

__global__ __launch_bounds__(256) void hist_kernel(
    const int* __restrict__ ei, const int* __restrict__ i64flag,
    int* __restrict__ counts, int E)
{
    int e = blockIdx.x * 256 + threadIdx.x;
    if (e >= E) return;
    int d = (*i64flag) ? ei[2 * (size_t)E + 2 * (size_t)e] : ei[(size_t)E + e];
    atomicAdd(&counts[d], 1);
}

// block-level inclusive scan; writes per-element exclusive offsets + block totals
__global__ __launch_bounds__(256) void scan1_kernel(
    const int* __restrict__ counts, int* __restrict__ offs,
    int* __restrict__ bsum, int N)
{
    __shared__ int s[256];
    int tid = threadIdx.x;
    int i = blockIdx.x * 256 + tid;
    int c = (i < N) ? counts[i] : 0;
    s[tid] = c;
    __syncthreads();
#pragma unroll
    for (int off = 1; off < 256; off <<= 1) {
        int add = (tid >= off) ? s[tid - off] : 0;
        __syncthreads();
        s[tid] += add;
        __syncthreads();
    }
    int incl = s[tid];
    if (i < N) offs[i] = incl - c;            // exclusive within block
    if (tid == 255) bsum[blockIdx.x] = incl;  // block total
}

// merged scan2+scan3: every block re-scans the (<=256) block sums in LDS,
// adds its prefix to offs, fills cursor, and block 0 writes offs[N] = E.
__global__ __launch_bounds__(256) void scan23_kernel(
    int* __restrict__ offs, const int* __restrict__ bsum,
    int* __restrict__ cursor, int N, int E, int nb)
{
    __shared__ int s[256];
    int tid = threadIdx.x;
    int v = (tid < nb) ? bsum[tid] : 0;
    s[tid] = v;
    __syncthreads();
#pragma unroll
    for (int off = 1; off < 256; off <<= 1) {
        int add = (tid >= off) ? s[tid - off] : 0;
        __syncthreads();
        s[tid] += add;
        __syncthreads();
    }
    int pre = (blockIdx.x == 0) ? 0 : s[blockIdx.x - 1];
    int i = blockIdx.x * 256 + tid;
    if (i < N) {
        int o = offs[i] + pre;
        offs[i] = o;
        cursor[i] = o;
    }
    if (blockIdx.x == 0 && tid == 0) offs[N] = E;
}

// CSR scatter: el[slot] = (src, edge_id)
__global__ __launch_bounds__(256) void scatter_kernel(
    const int* __restrict__ ei, const int* __restrict__ i64flag,
    int* __restrict__ cursor, int2* __restrict__ el, int E)
{
    int e = blockIdx.x * 256 + threadIdx.x;
    if (e >= E) return;
    int s, d;
    if (*i64flag) {
        s = ei[2 * (size_t)e];
        d = ei[2 * (size_t)E + 2 * (size_t)e];
    } else {
        s = ei[e];
        d = ei[(size_t)E + e];
    }
    int pos = atomicAdd(&cursor[d], 1);
    el[pos] = make_int2(s, e);
}

// ---------------- fused aggregation + GEMM1 ----------------
// One block = 128 nodes. Phase A: aggregate each node's row directly into the
// LDS A-tile (no global t1). Phase B: 128x128 MFMA with W1, out t2 (bf16) +
// column stats. MODE 0 (layer 0): gather xb, read f32 ea via el[slot].y, and
// materialize eab (bf16, CSR slot order) + srcs. MODE 1 (layers 1,2): gather
// t3b with prev outer-BN affine folded, stream eab/srcs sequentially.
template<int MODE>
__global__ __launch_bounds__(512) void agf_kernel(
    const unsigned short* __restrict__ xg,   // [N][128] bf16 gather operand
    const float* __restrict__ ea,            // MODE 0 only
    unsigned short* __restrict__ eab,        // MODE 0: write; MODE 1: read
    int* __restrict__ srcs,                  // MODE 0: write; MODE 1: read
    const int2* __restrict__ el,             // MODE 0 only
    const int* __restrict__ offs,            // [N+1]
    const float* __restrict__ statsIn, const float* __restrict__ gamma,
    const float* __restrict__ beta,          // MODE 1 only
    const unsigned short* __restrict__ Wt,   // [128][128] bf16 [c][k]
    const float* __restrict__ bias,
    unsigned short* __restrict__ t2out, float* __restrict__ statsOut, int N)
{
    __shared__ __attribute__((aligned(16))) unsigned short As[128][136];
    __shared__ __attribute__((aligned(16))) unsigned short Ws[128][136];
    __shared__ float u0[128], u1[128];
    __shared__ float sc[128], sh[128];
    const int tid = threadIdx.x;
    const int row0 = blockIdx.x * 128;

    if (MODE == 1) {
        if (tid < 128) {
            float inv = 1.f / (float)N;
            float m = statsIn[tid] * inv;
            float v = statsIn[128 + tid] * inv - m * m;
            v = fmaxf(v, 0.f);
            float rs = rsqrtf(v + 1e-5f);
            float gr = gamma[tid] * rs;
            sc[tid] = gr;
            sh[tid] = beta[tid] - m * gr;
        }
    }
    // stage Ws (bf16 copy, coalesced)
#pragma unroll
    for (int it = 0; it < 4; ++it) {
        int lin = (it * 512 + tid) * 8;
        int c = lin >> 7;
        int k = lin & 127;
        *(uint4*)&Ws[c][k] = *(const uint4*)(Wt + (size_t)c * 128 + k);
    }
    if (tid < 128) { u0[tid] = 0.f; u1[tid] = 0.f; }
    __syncthreads();

    const int lane = tid & 63;
    const int half = lane >> 5;
    const int l32  = lane & 31;
    const int d0   = l32 * 4;
    const int wv   = tid >> 6;          // wave 0..7, owns node rows wv*16..+15

    f32x4 scv = {1.f, 1.f, 1.f, 1.f}, shv = {0.f, 0.f, 0.f, 0.f};
    if (MODE == 1) {
        scv = *(const f32x4*)(sc + d0);
        shv = *(const f32x4*)(sh + d0);
    }

    // ---- Phase A: aggregate 16 nodes per wave into As ----
    for (int t = 0; t < 16; ++t) {
        const int r = wv * 16 + t;
        const int n = row0 + r;
        f32x4 acc = {0.f, 0.f, 0.f, 0.f};
        if (n < N) {
            const int start = offs[n];
            const int deg   = offs[n + 1] - start;
            const int mid = (deg + 1) >> 1;
            int j        = half ? mid : 0;
            const int hi = half ? deg : mid;

            if (half == 0) {
                u16x4 cv = *(const u16x4*)(xg + (size_t)n * 128 + d0);
#pragma unroll
                for (int q = 0; q < 4; ++q) {
                    float f = bf2f(cv[q]);
                    if (MODE == 1) f = fmaxf(fmaf(f, scv[q], shv[q]), 0.f);
                    acc[q] = f;
                }
            }

#define APPLY(GXV, AV) { \
    _Pragma("unroll") \
    for (int q = 0; q < 4; ++q) { \
        float gx = bf2f((GXV)[q]); \
        if (MODE == 1) gx = fmaxf(fmaf(gx, scv[q], shv[q]), 0.f); \
        acc[q] += fmaxf(gx + (AV)[q], 0.f); \
    } }

            if (MODE == 0) {
                for (; j + 3 < hi; j += 4) {
                    int2 e0 = el[start + j + 0];
                    int2 e1 = el[start + j + 1];
                    int2 e2 = el[start + j + 2];
                    int2 e3 = el[start + j + 3];
                    u16x4 x0 = *(const u16x4*)(xg + (size_t)e0.x * 128 + d0);
                    u16x4 x1 = *(const u16x4*)(xg + (size_t)e1.x * 128 + d0);
                    u16x4 x2 = *(const u16x4*)(xg + (size_t)e2.x * 128 + d0);
                    u16x4 x3 = *(const u16x4*)(xg + (size_t)e3.x * 128 + d0);
                    f32x4 a0 = __builtin_nontemporal_load((const f32x4*)(ea + (size_t)e0.y * 128 + d0));
                    f32x4 a1 = __builtin_nontemporal_load((const f32x4*)(ea + (size_t)e1.y * 128 + d0));
                    f32x4 a2 = __builtin_nontemporal_load((const f32x4*)(ea + (size_t)e2.y * 128 + d0));
                    f32x4 a3 = __builtin_nontemporal_load((const f32x4*)(ea + (size_t)e3.y * 128 + d0));
                    u16x4 b0, b1, b2, b3;
#pragma unroll
                    for (int q = 0; q < 4; ++q) {
                        b0[q] = f2bf(a0[q]); b1[q] = f2bf(a1[q]);
                        b2[q] = f2bf(a2[q]); b3[q] = f2bf(a3[q]);
                    }
                    __builtin_nontemporal_store(b0, (u16x4*)(eab + (size_t)(start + j + 0) * 128 + d0));
                    __builtin_nontemporal_store(b1, (u16x4*)(eab + (size_t)(start + j + 1) * 128 + d0));
                    __builtin_nontemporal_store(b2, (u16x4*)(eab + (size_t)(start + j + 2) * 128 + d0));
                    __builtin_nontemporal_store(b3, (u16x4*)(eab + (size_t)(start + j + 3) * 128 + d0));
                    if (l32 == 0) {
                        srcs[start + j + 0] = e0.x;
                        srcs[start + j + 1] = e1.x;
                        srcs[start + j + 2] = e2.x;
                        srcs[start + j + 3] = e3.x;
                    }
                    APPLY(x0, a0); APPLY(x1, a1); APPLY(x2, a2); APPLY(x3, a3);
                }
                for (; j < hi; ++j) {
                    int2 e0 = el[start + j];
                    u16x4 x0 = *(const u16x4*)(xg + (size_t)e0.x * 128 + d0);
                    f32x4 a0 = __builtin_nontemporal_load((const f32x4*)(ea + (size_t)e0.y * 128 + d0));
                    u16x4 b0;
#pragma unroll
                    for (int q = 0; q < 4; ++q) b0[q] = f2bf(a0[q]);
                    __builtin_nontemporal_store(b0, (u16x4*)(eab + (size_t)(start + j) * 128 + d0));
                    if (l32 == 0) srcs[start + j] = e0.x;
                    APPLY(x0, a0);
                }
            } else {
                for (; j + 3 < hi; j += 4) {
                    int s0 = srcs[start + j + 0];
                    int s1 = srcs[start + j + 1];
                    int s2 = srcs[start + j + 2];
                    int s3 = srcs[start + j + 3];
                    u16x4 x0 = *(const u16x4*)(xg + (size_t)s0 * 128 + d0);
                    u16x4 x1 = *(const u16x4*)(xg + (size_t)s1 * 128 + d0);
                    u16x4 x2 = *(const u16x4*)(xg + (size_t)s2 * 128 + d0);
                    u16x4 x3 = *(const u16x4*)(xg + (size_t)s3 * 128 + d0);
                    u16x4 g0 = __builtin_nontemporal_load((const u16x4*)(eab + (size_t)(start + j + 0) * 128 + d0));
                    u16x4 g1 = __builtin_nontemporal_load((const u16x4*)(eab + (size_t)(start + j + 1) * 128 + d0));
                    u16x4 g2 = __builtin_nontemporal_load((const u16x4*)(eab + (size_t)(start + j + 2) * 128 + d0));
                    u16x4 g3 = __builtin_nontemporal_load((const u16x4*)(eab + (size_t)(start + j + 3) * 128 + d0));
                    f32x4 a0, a1, a2, a3;
#pragma unroll
                    for (int q = 0; q < 4; ++q) {
                        a0[q] = bf2f(g0[q]); a1[q] = bf2f(g1[q]);
                        a2[q] = bf2f(g2[q]); a3[q] = bf2f(g3[q]);
                    }
                    APPLY(x0, a0); APPLY(x1, a1); APPLY(x2, a2); APPLY(x3, a3);
                }
                for (; j < hi; ++j) {
                    int s0 = srcs[start + j];
                    u16x4 x0 = *(const u16x4*)(xg + (size_t)s0 * 128 + d0);
                    u16x4 g0 = __builtin_nontemporal_load((const u16x4*)(eab + (size_t)(start + j) * 128 + d0));
                    f32x4 a0;
#pragma unroll
                    for (int q = 0; q < 4; ++q) a0[q] = bf2f(g0[q]);
                    APPLY(x0, a0);
                }
            }
#undef APPLY

#pragma unroll
            for (int q = 0; q < 4; ++q) acc[q] += __shfl_xor(acc[q], 32);
        }

        if (half == 0) {
            u16x4 o;
            o[0] = f2bf(acc[0]); o[1] = f2bf(acc[1]);
            o[2] = f2bf(acc[2]); o[3] = f2bf(acc[3]);
            *(u16x4*)&As[r][d0] = o;
        }
    }
    __syncthreads();

    // ---- Phase B: MFMA (out = As x Wt + bias), t2 bf16 + col stats ----
    const int quad = lane >> 4;
    const int m16  = lane & 15;

    bf16x8 af[4];
#pragma unroll
    for (int kk = 0; kk < 4; ++kk)
        af[kk] = *reinterpret_cast<const bf16x8*>(
            &As[wv * 16 + m16][kk * 32 + quad * 8]);

#pragma unroll
    for (int ct = 0; ct < 8; ++ct) {
        f32x4 acc = {0.f, 0.f, 0.f, 0.f};
#pragma unroll
        for (int kk = 0; kk < 4; ++kk) {
            bf16x8 bf = *reinterpret_cast<const bf16x8*>(&Ws[ct * 16 + m16][kk * 32 + quad * 8]);
            acc = __builtin_amdgcn_mfma_f32_16x16x32_bf16(af[kk], bf, acc, 0, 0, 0);
        }
        int col = ct * 16 + m16;
        float bb = bias[col];
        float s_part = 0.f, q_part = 0.f;
#pragma unroll
        for (int r = 0; r < 4; ++r) {
            int row = row0 + wv * 16 + quad * 4 + r;
            if (row < N) {
                float val = acc[r] + bb;
                t2out[(size_t)row * 128 + col] = f2bf(val);
                s_part += val;
                q_part += val * val;
            }
        }
        s_part += __shfl_xor(s_part, 16); q_part += __shfl_xor(q_part, 16);
        s_part += __shfl_xor(s_part, 32); q_part += __shfl_xor(q_part, 32);
        if (lane < 16) {
            atomicAdd(&u0[col], s_part);
            atomicAdd(&u1[col], q_part);
        }
    }
    __syncthreads();
    if (tid < 128) {
        atomicAdd(&statsOut[tid],       u0[tid]);
        atomicAdd(&statsOut[128 + tid], u1[tid]);
    }
}

// ---------------- GEMM 128x128 tile, 8 waves, fused BN-affine + col stats
// (used for gemm2) out[n][c] = sum_k relu(bn(inp))[n][k]*Wt[c][k] + bias[c].
template<bool OUTBF>
__global__ __launch_bounds__(512) void gemm2_kernel(
    const unsigned short* __restrict__ inp,   // [N][128] bf16
    const unsigned short* __restrict__ Wt,    // [128][128] bf16, [c][k]
    const float* __restrict__ bias,
    const float* __restrict__ statsIn,
    const float* __restrict__ gA, const float* __restrict__ bA,
    void* __restrict__ outv, float* __restrict__ statsOut, int N)
{
    __shared__ __attribute__((aligned(16))) unsigned short As[128][136];
    __shared__ __attribute__((aligned(16))) unsigned short Ws[128][136];
    __shared__ float u0[128], u1[128];
    const int tid = threadIdx.x;
    const int row0 = blockIdx.x * 128;

    if (tid < 128) {
        float inv = 1.f / (float)N;
        float m = statsIn[tid] * inv;
        float v = statsIn[128 + tid] * inv - m * m;
        v = fmaxf(v, 0.f);
        float rs = rsqrtf(v + 1e-5f);
        float gr = gA[tid] * rs;
        u0[tid] = gr;
        u1[tid] = bA[tid] - m * gr;
    }
    __syncthreads();

#pragma unroll
    for (int it = 0; it < 4; ++it) {
        int lin = (it * 512 + tid) * 8;
        int c = lin >> 7;
        int k = lin & 127;
        *(uint4*)&Ws[c][k] = *(const uint4*)(Wt + (size_t)c * 128 + k);
    }
#pragma unroll
    for (int it = 0; it < 4; ++it) {
        int lin = (it * 512 + tid) * 8;
        int r = lin >> 7;
        int c = lin & 127;
        int row = row0 + r;
        if (row < N) {
            uint4 v = *(const uint4*)(inp + (size_t)row * 128 + c);
            const unsigned short* pv = (const unsigned short*)&v;
            unsigned short o[8];
#pragma unroll
            for (int q = 0; q < 8; ++q)
                o[q] = f2bf(fmaxf(fmaf(bf2f(pv[q]), u0[c + q], u1[c + q]), 0.f));
            *(uint4*)&As[r][c] = *(const uint4*)o;
        } else {
            uint4 z = {0u, 0u, 0u, 0u};
            *(uint4*)&As[r][c] = z;
        }
    }
    __syncthreads();
    if (tid < 128) { u0[tid] = 0.f; u1[tid] = 0.f; }
    __syncthreads();

    const int wave = tid >> 6;
    const int lane = tid & 63;
    const int quad = lane >> 4;
    const int m16  = lane & 15;

    bf16x8 af[4];
#pragma unroll
    for (int kk = 0; kk < 4; ++kk)
        af[kk] = *reinterpret_cast<const bf16x8*>(
            &As[wave * 16 + m16][kk * 32 + quad * 8]);

    float* outf = (float*)outv;
    unsigned short* outb = (unsigned short*)outv;

#pragma unroll
    for (int ct = 0; ct < 8; ++ct) {
        f32x4 acc = {0.f, 0.f, 0.f, 0.f};
#pragma unroll
        for (int kk = 0; kk < 4; ++kk) {
            bf16x8 bf = *reinterpret_cast<const bf16x8*>(&Ws[ct * 16 + m16][kk * 32 + quad * 8]);
            acc = __builtin_amdgcn_mfma_f32_16x16x32_bf16(af[kk], bf, acc, 0, 0, 0);
        }
        int col = ct * 16 + m16;
        float bb = bias[col];
        float s_part = 0.f, q_part = 0.f;
#pragma unroll
        for (int r = 0; r < 4; ++r) {
            int row = row0 + wave * 16 + quad * 4 + r;
            if (row < N) {
                float val = acc[r] + bb;
                if (OUTBF) outb[(size_t)row * 128 + col] = f2bf(val);
                else       outf[(size_t)row * 128 + col] = val;
                s_part += val;
                q_part += val * val;
            }
        }
        s_part += __shfl_xor(s_part, 16); q_part += __shfl_xor(q_part, 16);
        s_part += __shfl_xor(s_part, 32); q_part += __shfl_xor(q_part, 32);
        if (lane < 16) {
            atomicAdd(&u0[col], s_part);
            atomicAdd(&u1[col], q_part);
        }
    }
    __syncthreads();
    if (tid < 128) {
        atomicAdd(&statsOut[tid],       u0[tid]);
        atomicAdd(&statsOut[128 + tid], u1[tid]);
    }
}

// out = gamma * (t - mean) * rsqrt(var + eps) + beta  (final layer, no relu)
__global__ __launch_bounds__(256) void bn_kernel(
    const float* __restrict__ t, const float* __restrict__ sum, const float* __restrict__ sq,
    const float* __restrict__ gamma, const float* __restrict__ beta,
    float* __restrict__ out, int N, int nv4)
{
    __shared__ float sc[128], sh[128];
    int tid = threadIdx.x;
    if (tid < 128) {
        float inv = 1.f / (float)N;
        float m = sum[tid] * inv;
        float v = sq[tid] * inv - m * m;
        v = fmaxf(v, 0.f);
        float rs = rsqrtf(v + 1e-5f);
        float gr = gamma[tid] * rs;
        sc[tid] = gr;
        sh[tid] = beta[tid] - m * gr;
    }
    __syncthreads();
    int g = blockIdx.x * 256 + tid;
    if (g < nv4) {
        int c = (g & 31) * 4;
        float4 v = *(const float4*)(t + (size_t)g * 4);
        float4 o;
        o.x = v.x * sc[c + 0] + sh[c + 0];
        o.y = v.y * sc[c + 1] + sh[c + 1];
        o.z = v.z * sc[c + 2] + sh[c + 2];
        o.w = v.w * sc[c + 3] + sh[c + 3];
        *(float4*)(out + (size_t)g * 4) = o;
    }
}

extern "C" void kernel_launch(void* const* d_in, const int* in_sizes, int n_in,
                              void* d_out, int out_size, void* d_ws, size_t ws_size,
                              hipStream_t stream)
{
    const float* x  = (const float*)d_in[0];
    const int* ei   = (const int*)d_in[1];
    const float* ea = (const float*)d_in[2];
    // d_in[3] = batch (unused)
    const float* W1 = (const float*)d_in[4];
    const float* b1 = (const float*)d_in[5];
    const float* gm = (const float*)d_in[6];
    const float* bm = (const float*)d_in[7];
    const float* W2 = (const float*)d_in[8];
    const float* b2 = (const float*)d_in[9];
    const float* go = (const float*)d_in[10];
    const float* bo = (const float*)d_in[11];
    float* out = (float*)d_out;

    const int N = in_sizes[0] / 128;   // 50000
    const int E = in_sizes[2] / 128;   // 800000

    char* w = (char*)d_ws;
    float* t3f  = (float*)w;            w += (size_t)N * 128 * 4;   // layer-2 gemm2 out, f32
    unsigned short* t3b = (unsigned short*)w; w += (size_t)N * 128 * 2;  // layers 0/1 gemm2 out
    unsigned short* t2 = (unsigned short*)w; w += (size_t)N * 128 * 2;  // fused out, bf16
    unsigned short* xb = (unsigned short*)w; w += (size_t)N * 128 * 2;  // x bf16 (layer 0)
    unsigned short* Wt = (unsigned short*)w; w += (size_t)6 * 16384 * 2; // W bf16 [c][k]
    float* stats = (float*)w;           w += 1536 * 4;              // 6 x (sum[128], sq[128])
    int* i64flag = (int*)w;             w += 16;
    int* counts  = (int*)w;             w += (size_t)N * 4;
    int* offs    = (int*)w;             w += (size_t)(N + 16) * 4;  // N+1 entries
    int* cursor  = (int*)w;             w += (size_t)N * 4;
    int* bsum    = (int*)w;             w += 256 * 4;
    int* srcs    = (int*)w;             w += (size_t)E * 4;         // slot -> src
    int2* el     = (int2*)w;            w += (size_t)E * 8;         // CSR: (src, edge)
    unsigned short* eab = (unsigned short*)w; w += (size_t)E * 128 * 2;  // ea bf16, CSR order

    const int nv4 = N * 32;
    const int gElem = (nv4 + 255) / 256;
    const int gGemm = (N + 127) / 128;
    const int gEdge = (E + 255) / 256;
    const int nb    = (N + 255) / 256;
    const int gConv = (N * 16 + 255) / 256;
    const int gSetup = gConv > nb ? gConv : nb;

    // ---- CSR build + W/x pre-convert (all layer-invariant) ----
    setup_kernel<<<gSetup, 256, 0, stream>>>(ei, i64flag, counts, stats, W1, W2, Wt, x, xb, N);
    hist_kernel<<<gEdge, 256, 0, stream>>>(ei, i64flag, counts, E);
    scan1_kernel<<<nb, 256, 0, stream>>>(counts, offs, bsum, N);
    scan23_kernel<<<nb, 256, 0, stream>>>(offs, bsum, cursor, N, E, nb);
    scatter_kernel<<<gEdge, 256, 0, stream>>>(ei, i64flag, cursor, el, E);

    for (int i = 0; i < 3; ++i) {
        float* sMlp = stats + (size_t)i * 512;        // gemm1 output stats
        float* sOut = stats + (size_t)i * 512 + 256;  // gemm2 output stats

        if (i == 0) {
            agf_kernel<0><<<gGemm, 512, 0, stream>>>(
                xb, ea, eab, srcs, el, offs, nullptr, nullptr, nullptr,
                Wt + (size_t)0 * 16384, b1 + 0, t2, sMlp, N);
        } else {
            float* sPrev = stats + (size_t)(i - 1) * 512 + 256;
            agf_kernel<1><<<gGemm, 512, 0, stream>>>(
                t3b, nullptr, eab, srcs, nullptr, offs,
                sPrev, go + (i - 1) * 128, bo + (i - 1) * 128,
                Wt + (size_t)i * 16384, b1 + i * 128, t2, sMlp, N);
        }
        // gemm2: BN1+relu on t2; layers 0/1 -> t3b (bf16), layer 2 -> t3f (f32)
        if (i < 2) {
            gemm2_kernel<true><<<gGemm, 512, 0, stream>>>(
                t2, Wt + (size_t)(i + 3) * 16384, b2 + i * 128,
                sMlp, gm + i * 128, bm + i * 128, t3b, sOut, N);
        } else {
            gemm2_kernel<false><<<gGemm, 512, 0, stream>>>(
                t2, Wt + (size_t)(i + 3) * 16384, b2 + i * 128,
                sMlp, gm + i * 128, bm + i * 128, t3f, sOut, N);
        }
    }
    // final outer BN (no relu) -> out
    bn_kernel<<<gElem, 256, 0, stream>>>(t3f, stats + 2 * 512 + 256, stats + 2 * 512 + 384,
                                         go + 256, bo + 256, out, N, nv4);
}

// Round 15
// 981.072 us; speedup vs baseline: 1.2191x; 1.0706x over previous
//
#include <hip/hip_runtime.h>

#define DEV __device__ __forceinline__

typedef __bf16 bf16x8 __attribute__((ext_vector_type(8)));
typedef float f32x4 __attribute__((ext_vector_type(4)));
typedef unsigned short u16x4 __attribute__((ext_vector_type(4)));

DEV unsigned short f2bf(float f) {
    unsigned u = __builtin_bit_cast(unsigned, f);
    u += 0x7fffu + ((u >> 16) & 1u);   // round-to-nearest-even
    return (unsigned short)(u >> 16);
}

DEV float bf2f(unsigned short h) {
    unsigned u = (unsigned)h << 16;
    return __builtin_bit_cast(float, u);
}

// zero counts[N] + stats[1536]; pre-convert W1,W2 (6 mats) to bf16 [c][k];
// convert x -> xb bf16; block 0 detects int64-vs-int32 edge_index layout.
__global__ __launch_bounds__(256) void setup_kernel(
    const int* __restrict__ ei, int* __restrict__ flag,
    int* __restrict__ counts, float* __restrict__ stats,
    const float* __restrict__ W1, const float* __restrict__ W2,
    unsigned short* __restrict__ Wt,
    const float* __restrict__ x, unsigned short* __restrict__ xb, int N)
{
    int g = blockIdx.x * 256 + threadIdx.x;
    if (g < N) counts[g] = 0;
    if (g < 1536) stats[g] = 0.f;
    if (g < 12288) {                       // 6 mats x 16 k-groups x 128 cols
        int mat = g >> 11;
        int r = g & 2047;
        int c = r & 127;
        int kg = (r >> 7) * 8;
        const float* Wsrc = (mat < 3) ? (W1 + (size_t)mat * 16384)
                                      : (W2 + (size_t)(mat - 3) * 16384);
        unsigned short o[8];
#pragma unroll
        for (int q = 0; q < 8; ++q)
            o[q] = f2bf(Wsrc[(size_t)(kg + q) * 128 + c]);
        *(uint4*)(Wt + ((size_t)mat * 128 + c) * 128 + kg) = *(const uint4*)o;
    }
    // x -> xb bf16 (8 elems/thread); N*16 threads cover N*128
    if (g < N * 16) {
        size_t base = (size_t)g * 8;
        float4 a = *(const float4*)(x + base);
        float4 b = *(const float4*)(x + base + 4);
        unsigned short o[8];
        o[0] = f2bf(a.x); o[1] = f2bf(a.y); o[2] = f2bf(a.z); o[3] = f2bf(a.w);
        o[4] = f2bf(b.x); o[5] = f2bf(b.y); o[6] = f2bf(b.z); o[7] = f2bf(b.w);
        *(uint4*)(xb + base) = *(const uint4*)o;
    }
    if (blockIdx.x == 0 && threadIdx.x < 64) {
        int t = threadIdx.x;
        int v = (t < 32) ? ei[2 * t + 1] : 0;
        unsigned long long b = __ballot(v == 0);
        if (t == 0) *flag = (b == ~0ull) ? 1 : 0;
    }
}

__global__ __launch_bounds__(256) void hist_kernel(
    const int* __restrict__ ei, const int* __restrict__ i64flag,
    int* __restrict__ counts, int E)
{
    int e = blockIdx.x * 256 + threadIdx.x;
    if (e >= E) return;
    int d = (*i64flag) ? ei[2 * (size_t)E + 2 * (size_t)e] : ei[(size_t)E + e];
    atomicAdd(&counts[d], 1);
}

// block-level inclusive scan; writes per-element exclusive offsets + block totals
__global__ __launch_bounds__(256) void scan1_kernel(
    const int* __restrict__ counts, int* __restrict__ offs,
    int* __restrict__ bsum, int N)
{
    __shared__ int s[256];
    int tid = threadIdx.x;
    int i = blockIdx.x * 256 + tid;
    int c = (i < N) ? counts[i] : 0;
    s[tid] = c;
    __syncthreads();
#pragma unroll
    for (int off = 1; off < 256; off <<= 1) {
        int add = (tid >= off) ? s[tid - off] : 0;
        __syncthreads();
        s[tid] += add;
        __syncthreads();
    }
    int incl = s[tid];
    if (i < N) offs[i] = incl - c;            // exclusive within block
    if (tid == 255) bsum[blockIdx.x] = incl;  // block total
}

// merged scan2+scan3: every block re-scans the (<=256) block sums in LDS,
// adds its prefix to offs, fills cursor, and block 0 writes offs[N] = E.
__global__ __launch_bounds__(256) void scan23_kernel(
    int* __restrict__ offs, const int* __restrict__ bsum,
    int* __restrict__ cursor, int N, int E, int nb)
{
    __shared__ int s[256];
    int tid = threadIdx.x;
    int v = (tid < nb) ? bsum[tid] : 0;
    s[tid] = v;
    __syncthreads();
#pragma unroll
    for (int off = 1; off < 256; off <<= 1) {
        int add = (tid >= off) ? s[tid - off] : 0;
        __syncthreads();
        s[tid] += add;
        __syncthreads();
    }
    int pre = (blockIdx.x == 0) ? 0 : s[blockIdx.x - 1];
    int i = blockIdx.x * 256 + tid;
    if (i < N) {
        int o = offs[i] + pre;
        offs[i] = o;
        cursor[i] = o;
    }
    if (blockIdx.x == 0 && tid == 0) offs[N] = E;
}

// CSR scatter: el[slot] = (src, edge_id)
__global__ __launch_bounds__(256) void scatter_kernel(
    const int* __restrict__ ei, const int* __restrict__ i64flag,
    int* __restrict__ cursor, int2* __restrict__ el, int E)
{
    int e = blockIdx.x * 256 + threadIdx.x;
    if (e >= E) return;
    int s, d;
    if (*i64flag) {
        s = ei[2 * (size_t)e];
        d = ei[2 * (size_t)E + 2 * (size_t)e];
    } else {
        s = ei[e];
        d = ei[(size_t)E + e];
    }
    int pos = atomicAdd(&cursor[d], 1);
    el[pos] = make_int2(s, e);
}

// ---------------- aggregation ----------------
// t1[n] (bf16) = xbn[n] + sum_{slot in CSR[n]} relu(xbn[src] + ea_slot)
// MODE 0 (layer 0): no affine; ea_slot read f32 via el[slot].y (random row);
//   ALSO writes eab[slot] = bf16(ea_slot) -- sequential per node -- so later
//   layers stream it.
// MODE 1 (layers 1,2): affine (prev outer BN+ReLU folded); ea_slot read from
//   eab (bf16, sequential by slot -- half bytes, streaming).
// One wave per node; half-wave 0 takes the first ceil(deg/2) CSR slots,
// half 1 the rest. 4-edge unroll keeps 8 gathers in flight per half-wave.
template<int MODE>
__global__ __launch_bounds__(512) void agg_kernel(
    const unsigned short* __restrict__ xb, const float* __restrict__ ea,
    unsigned short* __restrict__ eab,
    const int2* __restrict__ el, const int* __restrict__ offs,
    const float* __restrict__ statsIn, const float* __restrict__ gamma,
    const float* __restrict__ beta,
    unsigned short* __restrict__ t1, int N)
{
    constexpr bool AFFINE = (MODE == 1);
    __shared__ float sc[128], sh[128];
    int tid = threadIdx.x;
    if (AFFINE) {
        if (tid < 128) {
            float inv = 1.f / (float)N;
            float m = statsIn[tid] * inv;
            float v = statsIn[128 + tid] * inv - m * m;
            v = fmaxf(v, 0.f);
            float rs = rsqrtf(v + 1e-5f);
            float gr = gamma[tid] * rs;
            sc[tid] = gr;
            sh[tid] = beta[tid] - m * gr;
        }
        __syncthreads();
    }

    const int lane = tid & 63;
    const int half = lane >> 5;
    const int l32  = lane & 31;
    const int d0   = l32 * 4;

    f32x4 scv = {1.f, 1.f, 1.f, 1.f}, shv = {0.f, 0.f, 0.f, 0.f};
    if (AFFINE) {
        scv = *(const f32x4*)(sc + d0);
        shv = *(const f32x4*)(sh + d0);
    }

    const int n = blockIdx.x * 8 + (tid >> 6);
    if (n >= N) return;

    const int start = offs[n];
    const int deg   = offs[n + 1] - start;
    const int mid = (deg + 1) >> 1;
    int j        = half ? mid : 0;
    const int hi = half ? deg : mid;

    f32x4 acc = {0.f, 0.f, 0.f, 0.f};
    if (half == 0) {
        u16x4 cv = *(const u16x4*)(xb + (size_t)n * 128 + d0);
#pragma unroll
        for (int q = 0; q < 4; ++q) {
            float f = bf2f(cv[q]);
            if (AFFINE) f = fmaxf(fmaf(f, scv[q], shv[q]), 0.f);
            acc[q] = f;
        }
    }

    // one edge at CSR slot S with x-row fragment GXV and ea f32x4 AV
#define APPLY(GXV, AV) { \
    _Pragma("unroll") \
    for (int q = 0; q < 4; ++q) { \
        float gx = bf2f((GXV)[q]); \
        if (AFFINE) gx = fmaxf(fmaf(gx, scv[q], shv[q]), 0.f); \
        acc[q] += fmaxf(gx + (AV)[q], 0.f); \
    } }

    if (MODE == 0) {
        for (; j + 3 < hi; j += 4) {
            int2 e0 = el[start + j + 0];
            int2 e1 = el[start + j + 1];
            int2 e2 = el[start + j + 2];
            int2 e3 = el[start + j + 3];
            u16x4 x0 = *(const u16x4*)(xb + (size_t)e0.x * 128 + d0);
            u16x4 x1 = *(const u16x4*)(xb + (size_t)e1.x * 128 + d0);
            u16x4 x2 = *(const u16x4*)(xb + (size_t)e2.x * 128 + d0);
            u16x4 x3 = *(const u16x4*)(xb + (size_t)e3.x * 128 + d0);
            f32x4 a0 = __builtin_nontemporal_load((const f32x4*)(ea + (size_t)e0.y * 128 + d0));
            f32x4 a1 = __builtin_nontemporal_load((const f32x4*)(ea + (size_t)e1.y * 128 + d0));
            f32x4 a2 = __builtin_nontemporal_load((const f32x4*)(ea + (size_t)e2.y * 128 + d0));
            f32x4 a3 = __builtin_nontemporal_load((const f32x4*)(ea + (size_t)e3.y * 128 + d0));
            u16x4 b0, b1, b2, b3;
#pragma unroll
            for (int q = 0; q < 4; ++q) {
                b0[q] = f2bf(a0[q]); b1[q] = f2bf(a1[q]);
                b2[q] = f2bf(a2[q]); b3[q] = f2bf(a3[q]);
            }
            __builtin_nontemporal_store(b0, (u16x4*)(eab + (size_t)(start + j + 0) * 128 + d0));
            __builtin_nontemporal_store(b1, (u16x4*)(eab + (size_t)(start + j + 1) * 128 + d0));
            __builtin_nontemporal_store(b2, (u16x4*)(eab + (size_t)(start + j + 2) * 128 + d0));
            __builtin_nontemporal_store(b3, (u16x4*)(eab + (size_t)(start + j + 3) * 128 + d0));
            APPLY(x0, a0); APPLY(x1, a1); APPLY(x2, a2); APPLY(x3, a3);
        }
        for (; j < hi; ++j) {
            int2 e0 = el[start + j];
            u16x4 x0 = *(const u16x4*)(xb + (size_t)e0.x * 128 + d0);
            f32x4 a0 = __builtin_nontemporal_load((const f32x4*)(ea + (size_t)e0.y * 128 + d0));
            u16x4 b0;
#pragma unroll
            for (int q = 0; q < 4; ++q) b0[q] = f2bf(a0[q]);
            __builtin_nontemporal_store(b0, (u16x4*)(eab + (size_t)(start + j) * 128 + d0));
            APPLY(x0, a0);
        }
    } else {
        for (; j + 3 < hi; j += 4) {
            int2 e0 = el[start + j + 0];
            int2 e1 = el[start + j + 1];
            int2 e2 = el[start + j + 2];
            int2 e3 = el[start + j + 3];
            u16x4 x0 = *(const u16x4*)(xb + (size_t)e0.x * 128 + d0);
            u16x4 x1 = *(const u16x4*)(xb + (size_t)e1.x * 128 + d0);
            u16x4 x2 = *(const u16x4*)(xb + (size_t)e2.x * 128 + d0);
            u16x4 x3 = *(const u16x4*)(xb + (size_t)e3.x * 128 + d0);
            u16x4 g0 = __builtin_nontemporal_load((const u16x4*)(eab + (size_t)(start + j + 0) * 128 + d0));
            u16x4 g1 = __builtin_nontemporal_load((const u16x4*)(eab + (size_t)(start + j + 1) * 128 + d0));
            u16x4 g2 = __builtin_nontemporal_load((const u16x4*)(eab + (size_t)(start + j + 2) * 128 + d0));
            u16x4 g3 = __builtin_nontemporal_load((const u16x4*)(eab + (size_t)(start + j + 3) * 128 + d0));
            f32x4 a0, a1, a2, a3;
#pragma unroll
            for (int q = 0; q < 4; ++q) {
                a0[q] = bf2f(g0[q]); a1[q] = bf2f(g1[q]);
                a2[q] = bf2f(g2[q]); a3[q] = bf2f(g3[q]);
            }
            APPLY(x0, a0); APPLY(x1, a1); APPLY(x2, a2); APPLY(x3, a3);
        }
        for (; j < hi; ++j) {
            int2 e0 = el[start + j];
            u16x4 x0 = *(const u16x4*)(xb + (size_t)e0.x * 128 + d0);
            u16x4 g0 = __builtin_nontemporal_load((const u16x4*)(eab + (size_t)(start + j) * 128 + d0));
            f32x4 a0;
#pragma unroll
            for (int q = 0; q < 4; ++q) a0[q] = bf2f(g0[q]);
            APPLY(x0, a0);
        }
    }
#undef APPLY

    // combine the two half-wave partial sums
#pragma unroll
    for (int q = 0; q < 4; ++q) acc[q] += __shfl_xor(acc[q], 32);

    if (half == 0) {
        u16x4 o;
        o[0] = f2bf(acc[0]); o[1] = f2bf(acc[1]);
        o[2] = f2bf(acc[2]); o[3] = f2bf(acc[3]);
        *(u16x4*)(t1 + (size_t)n * 128 + d0) = o;
    }
}

// ---------------- GEMM 128x128 tile, 8 waves, fused BN-affine + col stats
// out[n][c] = sum_k a[n][k]*Wt[c][k] + bias[c].  Wt bf16 [c][k]; inp bf16.
// BNA: a = bf16(relu(inp*sc+sh)); else a = inp.
// OUTBF: out stored bf16, else f32. Stats accumulate on pre-round f32 values.
template<bool BNA, bool OUTBF>
__global__ __launch_bounds__(512) void gemm_kernel(
    const unsigned short* __restrict__ inp,   // [N][128] bf16
    const unsigned short* __restrict__ Wt,    // [128][128] bf16, [c][k]
    const float* __restrict__ bias,           // [128] f32
    const float* __restrict__ statsIn,
    const float* __restrict__ gA, const float* __restrict__ bA,
    void* __restrict__ outv, float* __restrict__ statsOut, int N)
{
    __shared__ __attribute__((aligned(16))) unsigned short As[128][136];  // [r][k]
    __shared__ __attribute__((aligned(16))) unsigned short Ws[128][136];  // [c][k]
    __shared__ float u0[128], u1[128];  // BNA: sc/sh during staging; then stats
    const int tid = threadIdx.x;
    const int row0 = blockIdx.x * 128;

    if (BNA) {
        if (tid < 128) {
            float inv = 1.f / (float)N;
            float m = statsIn[tid] * inv;
            float v = statsIn[128 + tid] * inv - m * m;
            v = fmaxf(v, 0.f);
            float rs = rsqrtf(v + 1e-5f);
            float gr = gA[tid] * rs;
            u0[tid] = gr;
            u1[tid] = bA[tid] - m * gr;
        }
        __syncthreads();
    }

    // stage Wt -> Ws: 16384 elems, 512 thr x 8 elems x 4 iters
#pragma unroll
    for (int it = 0; it < 4; ++it) {
        int lin = (it * 512 + tid) * 8;
        int c = lin >> 7;
        int k = lin & 127;
        *(uint4*)&Ws[c][k] = *(const uint4*)(Wt + (size_t)c * 128 + k);
    }
    // stage A tile: 128x128 bf16, 4 iters (zero-pad tail rows)
#pragma unroll
    for (int it = 0; it < 4; ++it) {
        int lin = (it * 512 + tid) * 8;
        int r = lin >> 7;
        int c = lin & 127;
        int row = row0 + r;
        if (row < N) {
            uint4 v = *(const uint4*)(inp + (size_t)row * 128 + c);
            if (BNA) {
                const unsigned short* pv = (const unsigned short*)&v;
                unsigned short o[8];
#pragma unroll
                for (int q = 0; q < 8; ++q)
                    o[q] = f2bf(fmaxf(fmaf(bf2f(pv[q]), u0[c + q], u1[c + q]), 0.f));
                *(uint4*)&As[r][c] = *(const uint4*)o;
            } else {
                *(uint4*)&As[r][c] = v;
            }
        } else {
            uint4 z = {0u, 0u, 0u, 0u};
            *(uint4*)&As[r][c] = z;
        }
    }
    __syncthreads();
    // repurpose u0/u1 as column sum / sumsq accumulators
    if (tid < 128) { u0[tid] = 0.f; u1[tid] = 0.f; }
    __syncthreads();

    const int wave = tid >> 6;          // 0..7, owns rows wave*16..+15
    const int lane = tid & 63;
    const int quad = lane >> 4;
    const int m16  = lane & 15;

    bf16x8 af[4];
#pragma unroll
    for (int kk = 0; kk < 4; ++kk)
        af[kk] = *reinterpret_cast<const bf16x8*>(
            &As[wave * 16 + m16][kk * 32 + quad * 8]);

    float* outf = (float*)outv;
    unsigned short* outb = (unsigned short*)outv;

#pragma unroll
    for (int ct = 0; ct < 8; ++ct) {
        f32x4 acc = {0.f, 0.f, 0.f, 0.f};
#pragma unroll
        for (int kk = 0; kk < 4; ++kk) {
            bf16x8 bf = *reinterpret_cast<const bf16x8*>(&Ws[ct * 16 + m16][kk * 32 + quad * 8]);
            acc = __builtin_amdgcn_mfma_f32_16x16x32_bf16(af[kk], bf, acc, 0, 0, 0);
        }
        int col = ct * 16 + m16;
        float bb = bias[col];
        float s_part = 0.f, q_part = 0.f;
#pragma unroll
        for (int r = 0; r < 4; ++r) {
            int row = row0 + wave * 16 + quad * 4 + r;  // C/D: row = quad*4+reg
            if (row < N) {
                float val = acc[r] + bb;
                if (OUTBF) outb[(size_t)row * 128 + col] = f2bf(val);
                else       outf[(size_t)row * 128 + col] = val;
                s_part += val;
                q_part += val * val;
            }
        }
        // reduce over the 4 quad-groups that share this column (lanes ^16, ^32)
        s_part += __shfl_xor(s_part, 16); q_part += __shfl_xor(q_part, 16);
        s_part += __shfl_xor(s_part, 32); q_part += __shfl_xor(q_part, 32);
        if (lane < 16) {
            atomicAdd(&u0[col], s_part);
            atomicAdd(&u1[col], q_part);
        }
    }
    __syncthreads();
    if (tid < 128) {
        atomicAdd(&statsOut[tid],       u0[tid]);
        atomicAdd(&statsOut[128 + tid], u1[tid]);
    }
}

// out = gamma * (t - mean) * rsqrt(var + eps) + beta  (final layer, no relu)
__global__ __launch_bounds__(256) void bn_kernel(
    const float* __restrict__ t, const float* __restrict__ sum, const float* __restrict__ sq,
    const float* __restrict__ gamma, const float* __restrict__ beta,
    float* __restrict__ out, int N, int nv4)
{
    __shared__ float sc[128], sh[128];
    int tid = threadIdx.x;
    if (tid < 128) {
        float inv = 1.f / (float)N;
        float m = sum[tid] * inv;
        float v = sq[tid] * inv - m * m;
        v = fmaxf(v, 0.f);
        float rs = rsqrtf(v + 1e-5f);
        float gr = gamma[tid] * rs;
        sc[tid] = gr;
        sh[tid] = beta[tid] - m * gr;
    }
    __syncthreads();
    int g = blockIdx.x * 256 + tid;
    if (g < nv4) {
        int c = (g & 31) * 4;
        float4 v = *(const float4*)(t + (size_t)g * 4);
        float4 o;
        o.x = v.x * sc[c + 0] + sh[c + 0];
        o.y = v.y * sc[c + 1] + sh[c + 1];
        o.z = v.z * sc[c + 2] + sh[c + 2];
        o.w = v.w * sc[c + 3] + sh[c + 3];
        *(float4*)(out + (size_t)g * 4) = o;
    }
}

extern "C" void kernel_launch(void* const* d_in, const int* in_sizes, int n_in,
                              void* d_out, int out_size, void* d_ws, size_t ws_size,
                              hipStream_t stream)
{
    const float* x  = (const float*)d_in[0];
    const int* ei   = (const int*)d_in[1];
    const float* ea = (const float*)d_in[2];
    // d_in[3] = batch (unused)
    const float* W1 = (const float*)d_in[4];
    const float* b1 = (const float*)d_in[5];
    const float* gm = (const float*)d_in[6];
    const float* bm = (const float*)d_in[7];
    const float* W2 = (const float*)d_in[8];
    const float* b2 = (const float*)d_in[9];
    const float* go = (const float*)d_in[10];
    const float* bo = (const float*)d_in[11];
    float* out = (float*)d_out;

    const int N = in_sizes[0] / 128;   // 50000
    const int E = in_sizes[2] / 128;   // 800000

    char* w = (char*)d_ws;
    float* t3f  = (float*)w;            w += (size_t)N * 128 * 4;   // layer-2 gemm2 out, f32
    unsigned short* t3b = (unsigned short*)w; w += (size_t)N * 128 * 2;  // layers 0/1 gemm2 out
    unsigned short* t1 = (unsigned short*)w; w += (size_t)N * 128 * 2;  // agg out, bf16
    unsigned short* t2 = (unsigned short*)w; w += (size_t)N * 128 * 2;  // gemm1 out, bf16
    unsigned short* xb = (unsigned short*)w; w += (size_t)N * 128 * 2;  // x bf16 (layer 0)
    unsigned short* Wt = (unsigned short*)w; w += (size_t)6 * 16384 * 2; // W bf16 [c][k]
    float* stats = (float*)w;           w += 1536 * 4;              // 6 x (sum[128], sq[128])
    int* i64flag = (int*)w;             w += 16;
    int* counts  = (int*)w;             w += (size_t)N * 4;
    int* offs    = (int*)w;             w += (size_t)(N + 16) * 4;  // N+1 entries
    int* cursor  = (int*)w;             w += (size_t)N * 4;
    int* bsum    = (int*)w;             w += 256 * 4;
    int2* el     = (int2*)w;            w += (size_t)E * 8;         // CSR: (src, edge)
    unsigned short* eab = (unsigned short*)w; w += (size_t)E * 128 * 2;  // ea bf16, CSR order

    const int nv4 = N * 32;
    const int gElem = (nv4 + 255) / 256;
    const int gGemm = (N + 127) / 128;
    const int gEdge = (E + 255) / 256;
    const int nb    = (N + 255) / 256;
    const int gAgg  = (N + 7) / 8;
    const int gConv = (N * 16 + 255) / 256;
    const int gSetup = gConv > nb ? gConv : nb;

    // ---- CSR build + W/x pre-convert (all layer-invariant) ----
    setup_kernel<<<gSetup, 256, 0, stream>>>(ei, i64flag, counts, stats, W1, W2, Wt, x, xb, N);
    hist_kernel<<<gEdge, 256, 0, stream>>>(ei, i64flag, counts, E);
    scan1_kernel<<<nb, 256, 0, stream>>>(counts, offs, bsum, N);
    scan23_kernel<<<nb, 256, 0, stream>>>(offs, bsum, cursor, N, E, nb);
    scatter_kernel<<<gEdge, 256, 0, stream>>>(ei, i64flag, cursor, el, E);

    for (int i = 0; i < 3; ++i) {
        float* sMlp = stats + (size_t)i * 512;        // gemm1 output stats
        float* sOut = stats + (size_t)i * 512 + 256;  // gemm2 output stats

        if (i == 0) {
            // layer 0: f32 ea via el[].y; also materializes eab in CSR order
            agg_kernel<0><<<gAgg, 512, 0, stream>>>(
                xb, ea, eab, el, offs, nullptr, nullptr, nullptr, t1, N);
        } else {
            float* sPrev = stats + (size_t)(i - 1) * 512 + 256;
            // layers 1-2: stream eab (bf16, sequential by slot)
            agg_kernel<1><<<gAgg, 512, 0, stream>>>(
                t3b, nullptr, eab, el, offs, sPrev, go + (i - 1) * 128, bo + (i - 1) * 128, t1, N);
        }
        // gemm1: t1 (bf16) -> t2 (bf16), stats of t2 -> sMlp
        gemm_kernel<false, true><<<gGemm, 512, 0, stream>>>(
            t1, Wt + (size_t)i * 16384, b1 + i * 128,
            nullptr, nullptr, nullptr, t2, sMlp, N);
        // gemm2: BN1+relu applied to t2; layers 0/1 -> t3b (bf16), layer 2 -> t3f (f32)
        if (i < 2) {
            gemm_kernel<true, true><<<gGemm, 512, 0, stream>>>(
                t2, Wt + (size_t)(i + 3) * 16384, b2 + i * 128,
                sMlp, gm + i * 128, bm + i * 128, t3b, sOut, N);
        } else {
            gemm_kernel<true, false><<<gGemm, 512, 0, stream>>>(
                t2, Wt + (size_t)(i + 3) * 16384, b2 + i * 128,
                sMlp, gm + i * 128, bm + i * 128, t3f, sOut, N);
        }
    }
    // final outer BN (no relu) -> out
    bn_kernel<<<gElem, 256, 0, stream>>>(t3f, stats + 2 * 512 + 256, stats + 2 * 512 + 384,
                                         go + 256, bo + 256, out, N, nv4);
}